// Round 1
// baseline (38387.833 us; speedup 1.0000x reference)
//
#include <hip/hip_runtime.h>

// FlowRNN (GRU scan with flow-delta residual), MI355X gfx950 — round 3.
//
// vs round 2 (10.35 ms, MfmaUtil 0.8%, VALUBusy 1.6%, HBM 2.5%):
//   The counters showed the kernel was latency-bound on the cross-block ring
//   exchange (~24k cycles/step for ~250 cycles of MFMA work): sc1 store drain
//   -> L3 flag atomic (32 contended adds) -> polling -> sc1 ring loads.
//   This version DELETES all cross-block communication:
//   - 8 workgroups of 1024 threads (16 waves); each owns one batch-group of
//     16 rows and holds the ENTIRE weight set in VGPRs (96 bf16x8 frags =
//     384 VGPRs/thread; wave w owns hidden cols 16w..16w+15, i.e. the r, z, n
//     gate rows for those cols -> epilogue is fully lane-local).
//   - h / res / x_t broadcast through LDS (double-buffered), ONE
//     __syncthreads per step. No flags, no ring, no workspace.
//   - h_prev carried in registers per lane (f32), x(t+1) prefetched to regs
//     at step start and staged to LDS bf16 after the MFMA phase.

typedef __attribute__((ext_vector_type(8))) short bf16x8_t;   // 8 bf16 = 4 VGPRs
typedef __attribute__((ext_vector_type(4))) float f32x4_t;

#define MFMA16(a, b, c) __builtin_amdgcn_mfma_f32_16x16x32_bf16((a), (b), (c), 0, 0, 0)

constexpr int Bb = 128, Tt = 1024, Dd = 512, Hh = 256;
constexpr int NB = 8;          // one block per batch group
constexpr int ROWS = 16;       // batch rows per group (MFMA M)
constexpr int XST = 520;       // x LDS row stride (shorts): 1040 B, 16B-aligned, bank-uniform
constexpr int HST = 264;       // h/res LDS row stride (shorts): 528 B

__device__ __forceinline__ short f2bf(float f) {
  union { float f; unsigned int u; } v; v.f = f;
  unsigned int r = v.u + 0x7fffu + ((v.u >> 16) & 1u);   // RNE
  return (short)(r >> 16);
}

__device__ __forceinline__ bf16x8_t load8_bf(const float* p) {
  const f32x4_t a = *(const f32x4_t*)p;
  const f32x4_t b = *(const f32x4_t*)(p + 4);
  bf16x8_t r;
  r[0] = f2bf(a[0]); r[1] = f2bf(a[1]); r[2] = f2bf(a[2]); r[3] = f2bf(a[3]);
  r[4] = f2bf(b[0]); r[5] = f2bf(b[1]); r[6] = f2bf(b[2]); r[7] = f2bf(b[3]);
  return r;
}

__global__ __launch_bounds__(1024, 1)
void flowrnn_scan(const float* __restrict__ x, const float* __restrict__ w_ih,
                  const float* __restrict__ w_hh, const float* __restrict__ b_ih,
                  const float* __restrict__ b_hh, float* __restrict__ out) {
  __shared__ short xs[2][ROWS][XST];    // x_t bf16, double-buffered
  __shared__ short hsb[2][ROWS][HST];   // h_{t-1} bf16
  __shared__ short rsb[2][ROWS][HST];   // res_t bf16

  const int tid  = threadIdx.x;
  const int wid  = tid >> 6;            // wave 0..15, owns hidden cols 16*wid..+15
  const int lane = tid & 63;
  const int n16  = lane & 15;
  const int q    = lane >> 4;
  const int g    = blockIdx.x;          // batch group

  float* rout = out + (size_t)Bb * Tt * Hh;   // residual_output

  // ---- persistent weight B-fragments: 96 frags = 384 VGPRs/thread ----
  // B-frag layout (16x16x32): lane holds W[grow + n16][k0 + q*8 .. +7].
  // Wave w's three gate rows: r: 16w.., z: 256+16w.., n: 512+16w..
  bf16x8_t bx[3][16];   // w_ih x-part   (K = 512, input cols 256..767)
  bf16x8_t br[3][8];    // w_ih res-part (K = 256, input cols 0..255)
  bf16x8_t bh[3][8];    // w_hh          (K = 256)
  {
    const int gr0 = 16 * wid + n16;
#pragma unroll
    for (int gi = 0; gi < 3; ++gi) {
      const int grow = gi * 256 + gr0;
      const float* wi = w_ih + (size_t)grow * 768;
      const float* wh = w_hh + (size_t)grow * 256;
#pragma unroll
      for (int c = 0; c < 16; ++c) bx[gi][c] = load8_bf(wi + 256 + c * 32 + q * 8);
#pragma unroll
      for (int c = 0; c < 8; ++c)  br[gi][c] = load8_bf(wi + c * 32 + q * 8);
#pragma unroll
      for (int c = 0; c < 8; ++c)  bh[gi][c] = load8_bf(wh + c * 32 + q * 8);
    }
  }

  // ---- per-lane biases (lane's hidden col j is fixed) ----
  const int j = 16 * wid + n16;
  const float bR  = b_ih[j] + b_hh[j];
  const float bZ  = b_ih[256 + j] + b_hh[256 + j];
  const float bNX = b_ih[512 + j];
  const float bNH = b_hh[512 + j];

  // ---- zero initial state: h_{-1} = 0, res_0 = 0 ----
  for (int i = tid; i < ROWS * HST; i += 1024) {
    ((short*)hsb[0])[i] = 0;
    ((short*)rsb[0])[i] = 0;
  }

  // ---- x prefetch/stage for t = 0 (thread owns 8 floats of one row) ----
  const int xrow = tid >> 6;            // == wid, 16 rows
  const int xcol = (tid & 63) * 8;      // 64 threads/row * 8 = 512 cols
  const float* xbase = x + ((size_t)(g * ROWS + xrow) * Tt) * Dd + xcol;
  f32x4_t xpa = *(const f32x4_t*)xbase;
  f32x4_t xpb = *(const f32x4_t*)(xbase + 4);
  {
    bf16x8_t v;
    v[0] = f2bf(xpa[0]); v[1] = f2bf(xpa[1]); v[2] = f2bf(xpa[2]); v[3] = f2bf(xpa[3]);
    v[4] = f2bf(xpb[0]); v[5] = f2bf(xpb[1]); v[6] = f2bf(xpb[2]); v[7] = f2bf(xpb[3]);
    *(bf16x8_t*)&xs[0][xrow][xcol] = v;
  }

  float hprev[4] = {0.f, 0.f, 0.f, 0.f};   // own col j, rows q*4+0..3
  __syncthreads();

  for (int t = 0; t < Tt; ++t) {
    const int cur = t & 1, nxt = (t + 1) & 1;

    // 1) issue x(t+1) global prefetch (consumed after MFMA phase ~2k cycles later)
    if (t + 1 < Tt) {
      const f32x4_t* xp = (const f32x4_t*)(xbase + (size_t)(t + 1) * Dd);
      xpa = xp[0]; xpb = xp[1];
    }

    // 2) MFMA phase: A-frag = [row n16][k = c*32 + q*8 ..+7]
    f32x4_t aR  = {0.f, 0.f, 0.f, 0.f};
    f32x4_t aZ  = {0.f, 0.f, 0.f, 0.f};
    f32x4_t aNX = {0.f, 0.f, 0.f, 0.f};   // gx_n = res- + x-part (outside r-gate)
    f32x4_t aNH = {0.f, 0.f, 0.f, 0.f};   // gh_n (inside r-gate)
#pragma unroll
    for (int c = 0; c < 16; ++c) {
      bf16x8_t f = *(const bf16x8_t*)&xs[cur][n16][c * 32 + q * 8];
      aR  = MFMA16(f, bx[0][c], aR);
      aZ  = MFMA16(f, bx[1][c], aZ);
      aNX = MFMA16(f, bx[2][c], aNX);
    }
#pragma unroll
    for (int c = 0; c < 8; ++c) {
      bf16x8_t f = *(const bf16x8_t*)&rsb[cur][n16][c * 32 + q * 8];
      aR  = MFMA16(f, br[0][c], aR);
      aZ  = MFMA16(f, br[1][c], aZ);
      aNX = MFMA16(f, br[2][c], aNX);
    }
#pragma unroll
    for (int c = 0; c < 8; ++c) {
      bf16x8_t f = *(const bf16x8_t*)&hsb[cur][n16][c * 32 + q * 8];
      aR  = MFMA16(f, bh[0][c], aR);
      aZ  = MFMA16(f, bh[1][c], aZ);
      aNH = MFMA16(f, bh[2][c], aNH);
    }

    // 3) stage x(t+1) -> LDS bf16 (buffer nxt is free: its last reads were step t-1)
    if (t + 1 < Tt) {
      bf16x8_t v;
      v[0] = f2bf(xpa[0]); v[1] = f2bf(xpa[1]); v[2] = f2bf(xpa[2]); v[3] = f2bf(xpa[3]);
      v[4] = f2bf(xpb[0]); v[5] = f2bf(xpb[1]); v[6] = f2bf(xpb[2]); v[7] = f2bf(xpb[3]);
      *(bf16x8_t*)&xs[nxt][xrow][xcol] = v;
    }

    // 4) epilogue — fully lane-local (r/z/n for col j all in this lane)
#pragma unroll
    for (int i = 0; i < 4; ++i) {
      const int row = q * 4 + i;
      const float rg   = 1.f / (1.f + __expf(-(aR[i] + bR)));
      const float zg   = 1.f / (1.f + __expf(-(aZ[i] + bZ)));
      const float narg = (aNX[i] + bNX) + rg * (aNH[i] + bNH);
      const float e2   = __expf(2.f * narg);
      const float ng   = 1.f - 2.f / (e2 + 1.f);           // tanh
      const float h    = (1.f - zg) * ng + zg * hprev[i];
      const float rv   = h - hprev[i];                     // flow delta
      hprev[i] = h;

      const size_t b = (size_t)(g * ROWS + row);
      out[(b * Tt + t) * Hh + j] = h;
      if (t == 0)      rout[(b * Tt) * Hh + j] = 0.f;
      if (t + 1 < Tt)  rout[(b * Tt + t + 1) * Hh + j] = rv;

      hsb[nxt][row][j] = f2bf(h);
      rsb[nxt][row][j] = f2bf(rv);
    }

    __syncthreads();   // one barrier per step: publishes h/res/x(t+1) to all waves
  }
}

extern "C" void kernel_launch(void* const* d_in, const int* in_sizes, int n_in,
                              void* d_out, int out_size, void* d_ws, size_t ws_size,
                              hipStream_t stream) {
  (void)in_sizes; (void)n_in; (void)out_size; (void)d_ws; (void)ws_size;
  const float* x    = (const float*)d_in[0];
  const float* w_ih = (const float*)d_in[1];
  const float* w_hh = (const float*)d_in[2];
  const float* b_ih = (const float*)d_in[3];
  const float* b_hh = (const float*)d_in[4];
  float* out = (float*)d_out;

  flowrnn_scan<<<NB, 1024, 0, stream>>>(x, w_ih, w_hh, b_ih, b_hh, out);
}

// Round 2
// 14028.125 us; speedup vs baseline: 2.7365x; 2.7365x over previous
//
#include <hip/hip_runtime.h>

// FlowRNN (GRU scan with flow-delta residual), MI355X gfx950 — round 4.
//
// Round-3 failure: 16-wave block capped VGPRs at 128/thread -> all weight
// frags spilled to scratch (VGPR_Count=64, 38 ms). Single-CU is also
// compute-infeasible (103 GFLOP recurrent / 9.8 TF per CU = 10.6 ms).
// => spread compute over 16 CUs and make the cross-CU exchange fast.
//
// Structure:
//  - Pre-pass kernel converts x fp32 -> bf16 once (xbf). Scan reads A-frags
//    for the x-GEMM directly from xbf (no per-step f2bf, no x LDS staging).
//    xbf lives in workspace if large enough, else aliased over rout
//    (byte-identical row layout; safety proven by the flag ordering below).
//  - 16 blocks x 256 thr (4 waves). Block owns 16 hidden cols, all 128 rows.
//    Wave w owns rows 32w..32w+31 (2 M-tiles). Recurrent B-frags (res+h,
//    48 frags = 192 VGPR) register-resident; x B-frags (48 frags) in LDS.
//  - Exchange: per-WAVE single-writer flags (64 flags == 64 lanes -> one
//    parallel poll load, no atomic RMW, no contention). Ring h/res bf16
//    double-buffered in ws, sc1 write-through stores / sc1 loads.
//  - Order per step t: xMFMA(t) -> poll(all flags>=t+1) -> ring loads ->
//    recMFMA -> issue xbf(t+1) loads -> epilogue -> ring stores ->
//    s_waitcnt(0) -> flag=t+2 -> out(t) + rout(t) stores (rout deferred one
//    step: flag t+2 implies that wave's xbf(t+1) loads completed, so writing
//    rout[t] after poll(>=t+1) can never clobber unread xbf data).

typedef __attribute__((ext_vector_type(8))) short bf16x8_t;   // 8 bf16 = 4 VGPRs
typedef __attribute__((ext_vector_type(4))) float f32x4_t;

#define MFMA16(a, b, c) __builtin_amdgcn_mfma_f32_16x16x32_bf16((a), (b), (c), 0, 0, 0)

constexpr int Bb = 128, Tt = 1024, Dd = 512, Hh = 256;
constexpr int NBLK = 16;                              // block owns 16 hidden cols
constexpr size_t RING_OFF   = 4096;                   // after flag page
constexpr size_t RING_BYTES = (size_t)2 * 2 * Bb * Hh * 2;   // {h,res} x 2 slots bf16
constexpr size_t XBF_OFF    = RING_OFF + RING_BYTES;  // 266240 (16B aligned)
constexpr size_t XBF_BYTES  = (size_t)Bb * Tt * Dd * 2;      // 134 MB

__device__ __forceinline__ short f2bf(float f) {
  union { float f; unsigned u; } v; v.f = f;
  unsigned r = v.u + 0x7fffu + ((v.u >> 16) & 1u);    // RNE
  return (short)(r >> 16);
}

__device__ __forceinline__ bf16x8_t load8_bf(const float* p) {
  f32x4_t a = *(const f32x4_t*)p, b = *(const f32x4_t*)(p + 4);
  bf16x8_t r;
  r[0] = f2bf(a[0]); r[1] = f2bf(a[1]); r[2] = f2bf(a[2]); r[3] = f2bf(a[3]);
  r[4] = f2bf(b[0]); r[5] = f2bf(b[1]); r[6] = f2bf(b[2]); r[7] = f2bf(b[3]);
  return r;
}

// 16B ring fragment load bypassing L1/L2 (two 8B relaxed agent atomic loads)
__device__ __forceinline__ bf16x8_t ringload(const unsigned short* p) {
  unsigned long long lo = __hip_atomic_load((const unsigned long long*)p,
                                            __ATOMIC_RELAXED, __HIP_MEMORY_SCOPE_AGENT);
  unsigned long long hi = __hip_atomic_load((const unsigned long long*)(p + 4),
                                            __ATOMIC_RELAXED, __HIP_MEMORY_SCOPE_AGENT);
  union { unsigned long long u[2]; bf16x8_t v; } r;
  r.u[0] = lo; r.u[1] = hi; return r.v;
}

__global__ void xconvert(const float* __restrict__ x, unsigned short* __restrict__ xbf) {
  size_t i = (size_t)blockIdx.x * blockDim.x + threadIdx.x;
  const size_t n8 = (size_t)Bb * Tt * Dd / 8;
  for (; i < n8; i += (size_t)gridDim.x * blockDim.x)
    *(bf16x8_t*)(xbf + i * 8) = load8_bf(x + i * 8);
}

__global__ __launch_bounds__(256, 1)
void flowrnn_scan(const float* __restrict__ w_ih, const float* __restrict__ w_hh,
                  const float* __restrict__ b_ih, const float* __restrict__ b_hh,
                  const unsigned short* __restrict__ xbf, float* __restrict__ out,
                  unsigned int* __restrict__ flags, unsigned short* __restrict__ ring) {
  __shared__ bf16x8_t xBl[48 * 64];     // x-part B frags: [g*16+c][lane], 48 KiB

  const int tid  = threadIdx.x;
  const int wid  = tid >> 6;
  const int lane = tid & 63;
  const int n16  = lane & 15;
  const int q    = lane >> 4;
  const int bid  = blockIdx.x;
  const int J    = 16 * bid;
  const int j    = J + n16;             // this lane's hidden col

  unsigned short* hring = ring;                        // [2][Bb][Hh] bf16
  unsigned short* rring = ring + (size_t)2 * Bb * Hh;
  float* rout = out + (size_t)Bb * Tt * Hh;

  // ---- recurrent B frags in VGPRs: gate g row = g*256 + J + n16 ----
  bf16x8_t brA[3][8], bhA[3][8];
#pragma unroll
  for (int g = 0; g < 3; ++g) {
    const int grow = g * 256 + J + n16;
    const float* wi = w_ih + (size_t)grow * 768;
    const float* wh = w_hh + (size_t)grow * 256;
#pragma unroll
    for (int c = 0; c < 8; ++c) brA[g][c] = load8_bf(wi + c * 32 + q * 8);
#pragma unroll
    for (int c = 0; c < 8; ++c) bhA[g][c] = load8_bf(wh + c * 32 + q * 8);
  }
  // ---- x-part B frags -> LDS (wave w fills frag ids 12w..12w+11) ----
  for (int k = 0; k < 12; ++k) {
    const int f = 12 * wid + k, g = f >> 4, c = f & 15;
    const int grow = g * 256 + J + n16;
    xBl[f * 64 + lane] = load8_bf(w_ih + (size_t)grow * 768 + 256 + c * 32 + q * 8);
  }
  const float bR  = b_ih[j] + b_hh[j];
  const float bZ  = b_ih[256 + j] + b_hh[256 + j];
  const float bNX = b_ih[512 + j];
  const float bNH = b_hh[512 + j];
  __syncthreads();                      // xBl ready (only barrier in the kernel)

  // ---- xbf A-frag bases (rows 32w+16mt+n16) + t=0 prefetch ----
  const unsigned short* xr0 = xbf + (size_t)(32 * wid + n16) * Tt * Dd + q * 8;
  const unsigned short* xr1 = xbf + (size_t)(32 * wid + 16 + n16) * Tt * Dd + q * 8;
  bf16x8_t xa[2][16];
#pragma unroll
  for (int c = 0; c < 16; ++c) {
    xa[0][c] = *(const bf16x8_t*)(xr0 + c * 32);
    xa[1][c] = *(const bf16x8_t*)(xr1 + c * 32);
  }
  __builtin_amdgcn_s_waitcnt(0);        // xa(0) resident before init flag
  if (lane == 0)
    __hip_atomic_store(flags + (bid * 4 + wid), 1u,
                       __ATOMIC_RELAXED, __HIP_MEMORY_SCOPE_AGENT);

  float hprev[2][4] = {{0.f,0.f,0.f,0.f},{0.f,0.f,0.f,0.f}};
  float rvprev[2][4];
  long budget = 20000000;

  for (int t = 0; t < Tt; ++t) {
    f32x4_t aR[2], aZ[2], aNX[2], aNH[2];
#pragma unroll
    for (int mt = 0; mt < 2; ++mt) {
      aR[mt] = f32x4_t{0,0,0,0}; aZ[mt] = f32x4_t{0,0,0,0};
      aNX[mt] = f32x4_t{0,0,0,0}; aNH[mt] = f32x4_t{0,0,0,0};
    }

    // ---- x-part MFMAs (xa holds x(t); B from LDS) ----
#pragma unroll
    for (int c = 0; c < 16; ++c) {
      bf16x8_t b0 = xBl[(0 * 16 + c) * 64 + lane];
      bf16x8_t b1 = xBl[(1 * 16 + c) * 64 + lane];
      bf16x8_t b2 = xBl[(2 * 16 + c) * 64 + lane];
#pragma unroll
      for (int mt = 0; mt < 2; ++mt) {
        aR[mt]  = MFMA16(xa[mt][c], b0, aR[mt]);
        aZ[mt]  = MFMA16(xa[mt][c], b1, aZ[mt]);
        aNX[mt] = MFMA16(xa[mt][c], b2, aNX[mt]);
      }
    }

    // ---- poll: all 64 producer waves posted step t-1 (init counts as 1) ----
    {
      const unsigned tgt = (unsigned)(t + 1);
      for (;;) {
        unsigned v = __hip_atomic_load(flags + lane,
                                       __ATOMIC_RELAXED, __HIP_MEMORY_SCOPE_AGENT);
        if (__all((int)(v >= tgt))) break;
        if (--budget < 0) break;
      }
    }

    // ---- recurrent MFMAs from ring (h(t-1), res(t-1)) ----
    if (t > 0) {
      const size_t sb = (size_t)((t - 1) & 1) * (Bb * Hh);
      bf16x8_t hf[2][8], rf[2][8];
#pragma unroll
      for (int mt = 0; mt < 2; ++mt) {
        const int row = 32 * wid + 16 * mt + n16;
        const unsigned short* hp_ = hring + sb + (size_t)row * Hh + q * 8;
        const unsigned short* rp_ = rring + sb + (size_t)row * Hh + q * 8;
#pragma unroll
        for (int c = 0; c < 8; ++c) {
          rf[mt][c] = ringload(rp_ + c * 32);
          hf[mt][c] = ringload(hp_ + c * 32);
        }
      }
#pragma unroll
      for (int c = 0; c < 8; ++c)
#pragma unroll
        for (int mt = 0; mt < 2; ++mt) {
          aR[mt]  = MFMA16(rf[mt][c], brA[0][c], aR[mt]);
          aZ[mt]  = MFMA16(rf[mt][c], brA[1][c], aZ[mt]);
          aNX[mt] = MFMA16(rf[mt][c], brA[2][c], aNX[mt]);
          aR[mt]  = MFMA16(hf[mt][c], bhA[0][c], aR[mt]);
          aZ[mt]  = MFMA16(hf[mt][c], bhA[1][c], aZ[mt]);
          aNH[mt] = MFMA16(hf[mt][c], bhA[2][c], aNH[mt]);
        }
    }

    // ---- issue xa(t+1) loads (before drain: flag t+2 => these completed) ----
    if (t + 1 < Tt) {
#pragma unroll
      for (int c = 0; c < 16; ++c) {
        xa[0][c] = *(const bf16x8_t*)(xr0 + (size_t)(t + 1) * Dd + c * 32);
        xa[1][c] = *(const bf16x8_t*)(xr1 + (size_t)(t + 1) * Dd + c * 32);
      }
    }

    // ---- epilogue: lane-local gates (acc row = q*4+i, col = n16 = own j) ----
    float hnew[2][4], rv[2][4];
#pragma unroll
    for (int mt = 0; mt < 2; ++mt)
#pragma unroll
      for (int i = 0; i < 4; ++i) {
        const float r    = 1.f / (1.f + __expf(-(aR[mt][i] + bR)));
        const float z    = 1.f / (1.f + __expf(-(aZ[mt][i] + bZ)));
        const float narg = (aNX[mt][i] + bNX) + r * (aNH[mt][i] + bNH);
        const float e2   = __expf(2.f * narg);
        const float n    = 1.f - 2.f / (e2 + 1.f);     // tanh
        const float h    = (1.f - z) * n + z * hprev[mt][i];
        hnew[mt][i] = h; rv[mt][i] = h - hprev[mt][i];
        hprev[mt][i] = h;
      }

    // ---- ring publish: pair cols via shfl; even lanes h, odd lanes res ----
    {
      const size_t sb = (size_t)(t & 1) * (Bb * Hh);
#pragma unroll
      for (int mt = 0; mt < 2; ++mt)
#pragma unroll
        for (int i = 0; i < 4; ++i) {
          const int row = 32 * wid + 16 * mt + q * 4 + i;
          unsigned hw = (unsigned)(unsigned short)f2bf(hnew[mt][i]);
          unsigned rw = (unsigned)(unsigned short)f2bf(rv[mt][i]);
          unsigned hp_ = (unsigned)__shfl_xor((int)hw, 1, 64);
          unsigned rp_ = (unsigned)__shfl_xor((int)rw, 1, 64);
          if (!(lane & 1)) {
            __hip_atomic_store((unsigned*)(hring + sb + (size_t)row * Hh + (J + n16)),
                               hw | (hp_ << 16),
                               __ATOMIC_RELAXED, __HIP_MEMORY_SCOPE_AGENT);
          } else {
            __hip_atomic_store((unsigned*)(rring + sb + (size_t)row * Hh + (J + n16 - 1)),
                               rp_ | (rw << 16),
                               __ATOMIC_RELAXED, __HIP_MEMORY_SCOPE_AGENT);
          }
        }
    }

    // ---- release: drain ring stores + xa loads, then single-writer flag ----
    __builtin_amdgcn_s_waitcnt(0);
    if (lane == 0)
      __hip_atomic_store(flags + (bid * 4 + wid), (unsigned)(t + 2),
                         __ATOMIC_RELAXED, __HIP_MEMORY_SCOPE_AGENT);

    // ---- fp32 outputs AFTER flag (drain in next step's shadow). rout is
    //      deferred one step so writes land only after poll(>=t+1). ----
#pragma unroll
    for (int mt = 0; mt < 2; ++mt)
#pragma unroll
      for (int i = 0; i < 4; ++i) {
        const int row = 32 * wid + 16 * mt + q * 4 + i;
        const size_t base = ((size_t)row * Tt + t) * Hh + j;
        out[base]  = hnew[mt][i];
        rout[base] = (t == 0) ? 0.f : rvprev[mt][i];
        rvprev[mt][i] = rv[mt][i];
      }
  }
}

extern "C" void kernel_launch(void* const* d_in, const int* in_sizes, int n_in,
                              void* d_out, int out_size, void* d_ws, size_t ws_size,
                              hipStream_t stream) {
  (void)in_sizes; (void)n_in; (void)out_size;
  const float* x    = (const float*)d_in[0];
  const float* w_ih = (const float*)d_in[1];
  const float* w_hh = (const float*)d_in[2];
  const float* b_ih = (const float*)d_in[3];
  const float* b_hh = (const float*)d_in[4];
  float* out = (float*)d_out;

  unsigned int* flags  = (unsigned int*)d_ws;
  unsigned short* ring = (unsigned short*)((char*)d_ws + RING_OFF);
  unsigned short* xbf  =
      (ws_size >= XBF_OFF + XBF_BYTES)
          ? (unsigned short*)((char*)d_ws + XBF_OFF)
          : (unsigned short*)(out + (size_t)Bb * Tt * Hh);   // alias rout (ordered-safe)

  hipMemsetAsync(d_ws, 0, 256, stream);                      // zero the 64 flags
  xconvert<<<2048, 256, 0, stream>>>(x, xbf);
  flowrnn_scan<<<NBLK, 256, 0, stream>>>(w_ih, w_hh, b_ih, b_hh, xbf, out, flags, ring);
}